// Round 3
// baseline (947.928 us; speedup 1.0000x reference)
//
#include <hip/hip_runtime.h>
#include <hip/hip_bf16.h>
#include <stdint.h>

// x:(4,4096,4096) f32, weight:(4096,4096) f32, bias:(4096,) f32,
// fixed_base:(32,) f32, fixed_sign_flag:(32,) f32 -> out:(4,4096,4096) f32.
// M=16384, N=4096, K=4096. Group size 128.
#define H_DIM   4096
#define OUT_DIM 4096
#define M_TOTAL 16384
#define NGROUP  32
#define GSZ     128

// 256x256 tile, BK=64, 8 waves (2M x 4N), 512 threads.
// MFMA shape: 32x32x16 (ceiling 2382-2495 TF vs 16x16's 2075-2176; half the
// instruction count at identical LDS traffic).
#define BM 256
#define BN 256
#define BK 64
#define NT (H_DIM / BK)   // 64 K-tiles

typedef float  f32x16 __attribute__((ext_vector_type(16)));
typedef __bf16 bf16x8 __attribute__((ext_vector_type(8)));

__device__ __forceinline__ void ld_g2l_16(const void* gptr, void* ldsptr) {
  __builtin_amdgcn_global_load_lds(
      (const __attribute__((address_space(1))) uint32_t*)gptr,
      (__attribute__((address_space(3))) uint32_t*)ldsptr,
      16, 0, 0);
}

// ---------------------------------------------------------------------------
// Fused pre-pass: quant(x)->bf16 xq  AND  weight f32->bf16 wq, one dispatch.
__global__ void prep_kernel(const float* __restrict__ x,
                            const float* __restrict__ fixed_base,
                            const float* __restrict__ fixed_sign,
                            __hip_bfloat16* __restrict__ xq,
                            const float* __restrict__ w,
                            __hip_bfloat16* __restrict__ wq) {
  const int tid = threadIdx.x;
  const int NVB_Q = (M_TOTAL * NGROUP) / 8;           // 65536
  const int NVB   = NVB_Q + (OUT_DIM * H_DIM) / 2048; // +8192
  for (int vb = blockIdx.x; vb < NVB; vb += gridDim.x) {
    if (vb < NVB_Q) {
      const long gi  = (long)vb * 8 + (tid >> 5);
      const int  lg  = tid & 31;
      const int  g   = (int)(gi & (NGROUP - 1));
      const long off = (gi >> 5) * H_DIM + (long)g * GSZ + lg * 4;

      const float4 xv = *(const float4*)(x + off);
      const float  s  = fixed_sign[g];
      const float  b  = fixed_base[g];
      const float  hb = b * 0.5f;
      const float  sb = s * b;

      float q[4], r[4];
      const float xin[4] = {xv.x, xv.y, xv.z, xv.w};
#pragma unroll
      for (int k = 0; k < 4; ++k) {
        q[k] = (xin[k] * s >= hb) ? 1.0f : 0.0f;
        r[k] = xin[k] - sb * q[k];
      }
      float m = fmaxf(fmaxf(fabsf(r[0]), fabsf(r[1])), fmaxf(fabsf(r[2]), fabsf(r[3])));
#pragma unroll
      for (int d = 16; d > 0; d >>= 1) m = fmaxf(m, __shfl_xor(m, d, 64));  // stays in 32-lane group
      m = fmaxf(m, 1e-8f);

      const float scale = m / 7.0f;
      const float inv_s = 7.0f / m;
      typedef __bf16 bf16x4 __attribute__((ext_vector_type(4)));
      bf16x4 o;
#pragma unroll
      for (int k = 0; k < 4; ++k) {
        float t = fminf(fmaxf(rintf(r[k] * inv_s), -8.0f), 7.0f);  // rintf = half-even = jnp.round
        o[k] = (__bf16)(q[k] * sb + t * scale);
      }
      *(bf16x4*)(xq + off) = o;
    } else {
      const size_t e  = ((size_t)(vb - NVB_Q) * 256 + tid) * 8;
      const float4 v0 = *(const float4*)(w + e);
      const float4 v1 = *(const float4*)(w + e + 4);
      bf16x8 o;
      o[0] = (__bf16)v0.x; o[1] = (__bf16)v0.y; o[2] = (__bf16)v0.z; o[3] = (__bf16)v0.w;
      o[4] = (__bf16)v1.x; o[5] = (__bf16)v1.y; o[6] = (__bf16)v1.z; o[7] = (__bf16)v1.w;
      *(bf16x8*)(wq + e) = o;
    }
  }
}

// ---------------------------------------------------------------------------
// GEMM: C[M,N] = A[M,K] * W[N,K]^T + bias, bf16 in / f32 out, 32x32x16 MFMA.
// Per wave: output 128x64 = 4m x 2n frags of 32x32; acc = 8 x f32x16.
// K-tile = 4 phases (ksub 0/1 x kstep 0/1, K=16 each):
//   [6 ds_read_b128 frags][STAGE half][opt vmcnt][BAR][lgkm0][prio1][8 MFMA][prio0][BAR]
// vmcnt ledger (per-wave outstanding, 2 ops/STAGE; 12 max in flight):
//   vmcnt(8)@P1(t): drains A-K1(t),B-K1(t) (staged P0/P1 of t-1) -> P2/P3(t) safe.
//   vmcnt(8)@P3(t): drains A-K0(t+1),B-K0(t+1) (staged P2/P3 of t) ... wait:
//     staged P2/P3(t), drained because the 8 newest are {A1(t+1),B1(t+1) would
//     not yet exist} -- outstanding at P3(t) = {A0(t+1),B0(t+1),A1(t+1),B1(t+1),
//     A0(t+2),B0(t+2)} = 12 -> drain 4 oldest = A0(t+1),B0(t+1). P0(t+1) safe.
//   Tail: VM4 @P3(62) drains K0(63); VM0 @P1(63) drains K1(63).
// LDS bank safety: 64 lanes of a frag read = 32 rows x 2 k-halves, XOR swizzle
// chunk^((row>>1)&3) balances 8 lanes per 16B slot -> schedulable conflict-free
// (same balance property as the 16x16 scheme that measured 0 conflicts).
#define VM8 0x0f78  /* vmcnt(8)  */
#define VM4 0x0f74  /* vmcnt(4)  */
#define VM0 0x0f70  /* vmcnt(0)  */
#define LGK 0xc07f  /* lgkmcnt(0) only */

#define BAR()   do { asm volatile("" ::: "memory"); __builtin_amdgcn_s_barrier(); \
                     asm volatile("" ::: "memory"); } while (0)
#define LGKM0() __builtin_amdgcn_s_waitcnt(LGK)
#define PRIO1() __builtin_amdgcn_s_setprio(1)
#define PRIO0() __builtin_amdgcn_s_setprio(0)

// stage one K-half: matrix X (0=A,1=B), dest buffer D, ksub S, k offset KT
#define STAGE(X, D, S, KT) do {                                                \
    const __hip_bfloat16* _gp = ((X) == 0 ? pA : pB) + (KT) + (S) * 32;        \
    __bf16* _lp = &lds[(X)][(D)][(S)][sR][sLC8];                               \
    ld_g2l_16(_gp, _lp);                                                       \
    ld_g2l_16(_gp + (size_t)128 * H_DIM, _lp + 128 * 32);                      \
  } while (0)

// One phase: frag reads (A 4 + B 2), optional stage, optional vmcnt, barrier,
// drain, 8 MFMA, barrier.  STX: -1 = no stage, 0 = A, 1 = B.
#define PHASE(D, KS, KP, STX, SD, SS, SKT, WVM) do {                           \
    _Pragma("unroll")                                                          \
    for (int _m = 0; _m < 4; ++_m)                                             \
      af[_m] = *(const bf16x8*)&lds[0][D][KS][rdA32 + _m * 32][ck[KP]];        \
    _Pragma("unroll")                                                          \
    for (int _n = 0; _n < 2; ++_n)                                             \
      bf[_n] = *(const bf16x8*)&lds[1][D][KS][rdB32 + _n * 32][ck[KP]];        \
    if ((STX) >= 0) { STAGE(STX, SD, SS, SKT); }                               \
    if (WVM) __builtin_amdgcn_s_waitcnt(WVM);                                  \
    BAR(); LGKM0(); PRIO1();                                                   \
    _Pragma("unroll")                                                          \
    for (int _m = 0; _m < 4; ++_m)                                             \
      _Pragma("unroll")                                                        \
      for (int _n = 0; _n < 2; ++_n)                                           \
        acc[_m][_n] = __builtin_amdgcn_mfma_f32_32x32x16_bf16(                 \
            af[_m], bf[_n], acc[_m][_n], 0, 0, 0);                             \
    PRIO0(); BAR();                                                            \
  } while (0)

#define TILE(D, SK1, KT1, SK0, KT0, VMA, VMB) do {                             \
    PHASE(D, 0, 0, (SK1) ? 0 : -1, (D) ^ 1, 1, KT1, 0);                        \
    PHASE(D, 0, 1, (SK1) ? 1 : -1, (D) ^ 1, 1, KT1, VMA);                      \
    PHASE(D, 1, 0, (SK0) ? 0 : -1, D,       0, KT0, 0);                        \
    PHASE(D, 1, 1, (SK0) ? 1 : -1, D,       0, KT0, VMB);                      \
  } while (0)

__global__ __launch_bounds__(512, 2)
void gemm_bt_kernel(const __hip_bfloat16* __restrict__ A,
                    const __hip_bfloat16* __restrict__ W,
                    const float* __restrict__ bias,
                    float* __restrict__ C) {
  __shared__ __bf16 lds[2][2][2][256][32];   // [mat][dbuf][ksub][row][k] = 128 KiB

  const int tid  = threadIdx.x;
  const int lane = tid & 63;
  const int wave = tid >> 6;
  const int l31  = lane & 31;
  const int hh   = lane >> 5;                // k-half within frag
  const int wm   = wave >> 2;                // 0..1 (M)
  const int wn   = wave & 3;                 // 0..3 (N)

  // XCD-aware bijective swizzle: 1024 blocks, 128 contiguous per XCD.
  const int bid = blockIdx.x;
  const int vid = (bid & 7) * 128 + (bid >> 3);
  const long rowBase = (long)(vid >> 4) * BM;
  const long colBase = (long)(vid & 15) * BN;

  // staging: thread covers rows sR,sR+128; LDS chunk tid&3 carries global
  // chunk (tid&3)^((sR>>1)&3)  [inverse of the read swizzle]
  const int sR   = tid >> 2;
  const int sLC8 = (tid & 3) * 8;
  const int sCg  = (tid & 3) ^ ((sR >> 1) & 3);
  const __hip_bfloat16* pA = A + (rowBase + sR) * H_DIM + sCg * 8;
  const __hip_bfloat16* pB = W + (colBase + sR) * H_DIM + sCg * 8;

  // frag reads: A row = wm*128 + m*32 + l31, k = ksub*32 + kp*16 + hh*8 (+j).
  // chunk4 = kp*2 + hh, stored at chunk4 ^ ((row>>1)&3); row>>1&3 == (l31>>1)&3.
  const int rdA32 = wm * 128 + l31;
  const int rdB32 = wn * 64 + l31;
  const int swz   = (l31 >> 1) & 3;
  int ck[2];
  ck[0] = ((0 * 2 + hh) ^ swz) * 8;
  ck[1] = ((1 * 2 + hh) ^ swz) * 8;

  f32x16 acc[4][2] = {};
  bf16x8 af[4], bf[2];

  // prologue: K0(0),K1(0),K0(1) staged (12 loads); vmcnt(8) -> K0(0) arrived.
  STAGE(0, 0, 0, 0);  STAGE(1, 0, 0, 0);
  STAGE(0, 0, 1, 0);  STAGE(1, 0, 1, 0);
  STAGE(0, 1, 0, BK); STAGE(1, 1, 0, BK);
  __builtin_amdgcn_s_waitcnt(VM8);
  BAR();

  // main loop: tiles 0..61 (2 per iteration, compile-time dbuf parity)
  for (int t = 0; t < NT - 2; t += 2) {
    TILE(0, true, (t + 1) * BK, true, (t + 2) * BK, VM8, VM8);
    TILE(1, true, (t + 2) * BK, true, (t + 3) * BK, VM8, VM8);
  }
  // tile 62: stage K1(63) only; VM4 drains K0(63) for tile 63's s0 phases
  TILE(0, true, (NT - 1) * BK, false, 0, VM8, VM4);
  // tile 63: no stages; VM0 at P1 drains K1(63) for its s1 phases
  TILE(1, false, 0, false, 0, VM0, VM0);

  // epilogue: C/D layout col = lane&31, row = (reg&3) + 8*(reg>>2) + 4*(lane>>5)
  // (m74/m101-verified). Nontemporal stores: C (267 MB stream) must not thrash
  // the LLC out of W/A panels.
#pragma unroll
  for (int m = 0; m < 4; ++m) {
#pragma unroll
    for (int n = 0; n < 2; ++n) {
      const long c  = colBase + wn * 64 + n * 32 + l31;
      const long r0 = rowBase + wm * 128 + m * 32 + 4 * hh;
      const float bv = bias[c];
#pragma unroll
      for (int rg = 0; rg < 16; ++rg) {
        const long row = r0 + (rg & 3) + 8 * (rg >> 2);
        __builtin_nontemporal_store(acc[m][n][rg] + bv, &C[row * OUT_DIM + c]);
      }
    }
  }
}

// ---------------------------------------------------------------------------
extern "C" void kernel_launch(void* const* d_in, const int* in_sizes, int n_in,
                              void* d_out, int out_size, void* d_ws, size_t ws_size,
                              hipStream_t stream) {
  const float* x          = (const float*)d_in[0];
  const float* weight     = (const float*)d_in[1];
  const float* bias       = (const float*)d_in[2];
  const float* fixed_base = (const float*)d_in[3];
  const float* fixed_sign = (const float*)d_in[4];
  float* out = (float*)d_out;

  __hip_bfloat16* xq = (__hip_bfloat16*)d_ws;                  // 128 MiB
  __hip_bfloat16* wq = xq + (size_t)M_TOTAL * H_DIM;           // +32 MiB

  prep_kernel<<<2048, 256, 0, stream>>>(x, fixed_base, fixed_sign, xq, weight, wq);

  gemm_bt_kernel<<<dim3((M_TOTAL / BM) * (OUT_DIM / BN)), 512, 0, stream>>>(xq, wq, bias, out);
}